// Round 4
// baseline (5451.962 us; speedup 1.0000x reference)
//
#include <hip/hip_runtime.h>

typedef short bf16x8 __attribute__((ext_vector_type(8)));
typedef float f32x4 __attribute__((ext_vector_type(4)));

#define BN_EPS 1e-5f
#define ELL_CAP 64

__device__ __forceinline__ unsigned short f2b(float x) {
    union { float f; unsigned u; } v; v.f = x;
    unsigned r = v.u + 0x7FFFu + ((v.u >> 16) & 1u);
    return (unsigned short)(r >> 16);
}
__device__ __forceinline__ float b2f(unsigned short h) {
    union { unsigned u; float f; } v; v.u = ((unsigned)h) << 16;
    return v.f;
}
__device__ __forceinline__ void atomAddF(float* p, float v) { unsafeAtomicAdd(p, v); }

__device__ __forceinline__ void gload16(const void* g, void* l) {
    __builtin_amdgcn_global_load_lds((const __attribute__((address_space(1))) void*)g,
                                     (__attribute__((address_space(3))) void*)l, 16, 0, 0);
}

// ---- W[k][ci][co] f32 -> WT[k][coPad][ciPad] bf16 (zero-padded both dims) ----
__global__ void transpose_cast_w(const float* __restrict__ W, unsigned short* __restrict__ WT,
                                 int Cin, int Cout, int CinPad, int CoutPad) {
    __shared__ float t[32][33];
    int co0 = blockIdx.x * 32, ci0 = blockIdx.y * 32, k = blockIdx.z;
    const float* Wk = W + (size_t)k * Cin * Cout;
    unsigned short* WTk = WT + (size_t)k * CoutPad * CinPad;
    int tc = threadIdx.x & 31, tr = threadIdx.x >> 5;
    for (int i = 0; i < 4; i++) {
        int r = tr + i * 8;
        int ci = ci0 + r, co = co0 + tc;
        t[r][tc] = (ci < Cin && co < Cout) ? Wk[(size_t)ci * Cout + co] : 0.f;
    }
    __syncthreads();
    for (int i = 0; i < 4; i++) {
        int r = tr + i * 8;
        WTk[(size_t)(co0 + r) * CinPad + ci0 + tc] = f2b(t[tc][r]);
    }
}

// ---- cast fp32 [N,Csrc] -> bf16 dst[n*stride + off + j], zero-fill j>=Csrc ----
__global__ void cast_cols(const float* __restrict__ src, unsigned short* __restrict__ dst,
                          int N, int Csrc, int stride, int off, int wid) {
    int i = blockIdx.x * blockDim.x + threadIdx.x;
    if (i >= N * wid) return;
    int n = i / wid, j = i % wid;
    float v = (j < Csrc) ? src[(size_t)n * Csrc + j] : 0.f;
    dst[(size_t)n * stride + off + j] = f2b(v);
}

// ---- BN stats standalone (used for dense s2 only) ----
__global__ void bn_stats(const float* __restrict__ x, float* __restrict__ stats,
                         int N, int C, int rowsPerBlock) {
    int r0 = blockIdx.x * rowsPerBlock;
    int r1 = min(N, r0 + rowsPerBlock);
    for (int c = threadIdx.x; c < C; c += blockDim.x) {
        float s = 0.f, s2 = 0.f;
        for (int r = r0; r < r1; r++) {
            float v = x[(size_t)r * C + c];
            s += v; s2 += v * v;
        }
        atomAddF(&stats[c], s);
        atomAddF(&stats[C + c], s2);
    }
}

// ---- BN apply + ReLU -> bf16 (strided dst, for concat), x4 vectorized ----
__global__ void bn_apply_bf16(const float* __restrict__ x, const float* __restrict__ stats,
                              const float* __restrict__ g, const float* __restrict__ b,
                              unsigned short* __restrict__ dst, int N, int C, int stride, float invN) {
    int i = blockIdx.x * blockDim.x + threadIdx.x;
    int C4 = C >> 2;
    if (i >= N * C4) return;
    int n = i / C4, cb = (i - n * C4) << 2;
    float4 xv = *(const float4*)(x + (size_t)n * C + cb);
    float vs[4] = {xv.x, xv.y, xv.z, xv.w};
    unsigned short os[4];
    #pragma unroll
    for (int j = 0; j < 4; j++) {
        int cc = cb + j;
        float mean = stats[cc] * invN;
        float var = stats[C + cc] * invN - mean * mean;
        float scale = g[cc] * rsqrtf(var + BN_EPS);
        float shift = b[cc] - mean * scale;
        os[j] = f2b(fmaxf(0.f, vs[j] * scale + shift));
    }
    ushort4 ov = {os[0], os[1], os[2], os[3]};
    *(ushort4*)(dst + (size_t)n * stride + cb) = ov;
}

// ---- BN apply + ReLU in-place fp32 (final output), x4 vectorized ----
__global__ void bn_apply_f32(float* __restrict__ x, const float* __restrict__ stats,
                             const float* __restrict__ g, const float* __restrict__ b,
                             int N, int C, float invN) {
    int i = blockIdx.x * blockDim.x + threadIdx.x;
    int C4 = C >> 2;
    if (i >= N * C4) return;
    int n = i / C4, cb = (i - n * C4) << 2;
    float* p = x + (size_t)n * C + cb;
    float4 xv = *(const float4*)p;
    float vs[4] = {xv.x, xv.y, xv.z, xv.w};
    #pragma unroll
    for (int j = 0; j < 4; j++) {
        int cc = cb + j;
        float mean = stats[cc] * invN;
        float var = stats[C + cc] * invN - mean * mean;
        float scale = g[cc] * rsqrtf(var + BN_EPS);
        float shift = b[cc] - mean * scale;
        vs[j] = fmaxf(0.f, vs[j] * scale + shift);
    }
    float4 ov = {vs[0], vs[1], vs[2], vs[3]};
    *(float4*)p = ov;
}

// ---- inverse-index (ELL) build: entry e = k*M+m ----
__global__ void ell_build(const int* __restrict__ out_idx, int total,
                          int* __restrict__ cnt, int* __restrict__ ell) {
    int e = blockIdx.x * blockDim.x + threadIdx.x;
    if (e >= total) return;
    int o = out_idx[e];
    int pos = atomicAdd(&cnt[o], 1);
    if (pos < ELL_CAP) ell[(size_t)o * ELL_CAP + pos] = e;
}

// ---- Phase B: per-output-row gather of bf16 partials (128-col chunk), fp32 sum,
//      single write; fused per-channel BN-stat accumulation on final k-chunk ----
__global__ __launch_bounds__(256)
void reduce_ell(const unsigned short* __restrict__ c, const int* __restrict__ cnt,
                const int* __restrict__ ell, float* __restrict__ out, float* __restrict__ stats,
                int n0, int Cout, int Nout, int k0row, int k1row, int accum, int addStats) {
    int wave = threadIdx.x >> 6, lane = threadIdx.x & 63;
    int qw = lane >> 4, lm = lane & 15;
    int colL = lm * 8, gcol = n0 + colL;
    float sS[8], sQ[8];
    #pragma unroll
    for (int j = 0; j < 8; j++) { sS[j] = 0.f; sQ[j] = 0.f; }
    for (int rr = 0; rr < 4; rr++) {
        int o = blockIdx.x * 64 + rr * 16 + wave * 4 + qw;
        if (o >= Nout) continue;
        float a[8];
        #pragma unroll
        for (int j = 0; j < 8; j++) a[j] = 0.f;
        int n = min(cnt[o], ELL_CAP);
        const int* ellrow = ell + (size_t)o * ELL_CAP;
        for (int i = 0; i < n; i++) {
            int e = ellrow[i];
            if (e < k0row || e >= k1row) continue;
            bf16x8 v = *(const bf16x8*)(c + (size_t)(e - k0row) * 128 + colL);
            #pragma unroll
            for (int j = 0; j < 8; j++) a[j] += b2f((unsigned short)v[j]);
        }
        if (gcol < Cout) {
            float* op = out + (size_t)o * Cout + gcol;
            if (accum) {
                float4 lo = *(const float4*)op;
                float4 hi = *(const float4*)(op + 4);
                a[0] += lo.x; a[1] += lo.y; a[2] += lo.z; a[3] += lo.w;
                a[4] += hi.x; a[5] += hi.y; a[6] += hi.z; a[7] += hi.w;
            }
            float4 lo = {a[0], a[1], a[2], a[3]}, hi = {a[4], a[5], a[6], a[7]};
            *(float4*)op = lo;
            *(float4*)(op + 4) = hi;
            if (addStats) {
                #pragma unroll
                for (int j = 0; j < 8; j++) { sS[j] += a[j]; sQ[j] += a[j] * a[j]; }
            }
        }
    }
    if (addStats) {
        #pragma unroll
        for (int j = 0; j < 8; j++) {
            float s = sS[j], q = sQ[j];
            s += __shfl_down(s, 32); q += __shfl_down(q, 32);
            s += __shfl_down(s, 16); q += __shfl_down(q, 16);
            if (qw == 0 && gcol < Cout) {
                atomAddF(&stats[gcol + j], s);
                atomAddF(&stats[Cout + gcol + j], q);
            }
        }
    }
}

// ---- Phase A: per-k dense GEMM, 128x128 tile, BK=32, double-buffered LDS,
//      single barrier per K-iter (prefetch issued after barrier) ----
template<bool DENSE>
__global__ __launch_bounds__(256)
void spconv_gemm(const unsigned short* __restrict__ A, const unsigned short* __restrict__ BT,
                 const int* __restrict__ in_idx, unsigned short* __restrict__ cpart,
                 float* __restrict__ outf, int M, int Kp, int CoutPad, int nbase, int kbase) {
    // seg-major 16B chunks: chunk(seg,row) = seg*128+row; global_load_lds lane-ordered,
    // 2-way-max bank aliasing on ds_read_b128 (measured 0 conflicts in r3).
    __shared__ __align__(16) unsigned short As[2 * 4096];
    __shared__ __align__(16) unsigned short Bs[2 * 4096];
    int tid = threadIdx.x, wave = tid >> 6, lane = tid & 63;
    int wr = wave >> 1, wc = wave & 1;
    int m0 = blockIdx.x * 128;
    int n0 = nbase + blockIdx.y * 128;
    int kzl = blockIdx.z, kz = kbase + kzl;

    int r0 = m0 + lane, r1 = r0 + 64;
    size_t arow0, arow1;
    if constexpr (DENSE) {
        arow0 = (size_t)min(r0, M - 1);
        arow1 = (size_t)min(r1, M - 1);
    } else {
        const int* idxk = in_idx + (size_t)kz * M;
        arow0 = (r0 < M) ? (size_t)idxk[r0] : 0;
        arow1 = (r1 < M) ? (size_t)idxk[r1] : 0;
    }
    const unsigned short* gA0 = A + arow0 * Kp + wave * 8;
    const unsigned short* gA1 = A + arow1 * Kp + wave * 8;
    const unsigned short* BTk = BT + (size_t)kz * CoutPad * Kp;
    const unsigned short* gB0 = BTk + (size_t)(n0 + lane) * Kp + wave * 8;
    const unsigned short* gB1 = BTk + (size_t)(n0 + 64 + lane) * Kp + wave * 8;
    unsigned short* lA0 = As + (wave * 128) * 8;
    unsigned short* lA1 = As + (wave * 128 + 64) * 8;
    unsigned short* lB0 = Bs + (wave * 128) * 8;
    unsigned short* lB1 = Bs + (wave * 128 + 64) * 8;

    f32x4 acc[4][4];
    #pragma unroll
    for (int i = 0; i < 4; i++)
        #pragma unroll
        for (int j = 0; j < 4; j++) acc[i][j] = (f32x4)(0.f);

    int laneM = lane & 15, seg = lane >> 4;
    int aoff = (seg * 128 + wr * 64 + laneM) * 8;
    int boff = (seg * 128 + wc * 64 + laneM) * 8;

    // prologue: stage k-step 0 into buf 0
    gload16(gA0, lA0);
    gload16(gA1, lA1);
    gload16(gB0, lB0);
    gload16(gB1, lB1);

    int nIter = Kp >> 5;
    for (int t = 0; t < nIter; t++) {
        __syncthreads();   // buf[t&1] complete (each wave drains own vmcnt at barrier)
        if (t + 1 < nIter) {       // prefetch next k-step into the other buffer;
            int kc = (t + 1) * 32; // flies during this iteration's MFMA phase
            int bo = ((t + 1) & 1) * 4096;
            gload16(gA0 + kc, lA0 + bo);
            gload16(gA1 + kc, lA1 + bo);
            gload16(gB0 + kc, lB0 + bo);
            gload16(gB1 + kc, lB1 + bo);
        }
        const unsigned short* ab = As + (t & 1) * 4096 + aoff;
        const unsigned short* bb = Bs + (t & 1) * 4096 + boff;
        bf16x8 af[4], bfr[4];
        #pragma unroll
        for (int i = 0; i < 4; i++) af[i] = *(const bf16x8*)(ab + i * 128);
        #pragma unroll
        for (int j = 0; j < 4; j++) bfr[j] = *(const bf16x8*)(bb + j * 128);
        #pragma unroll
        for (int i = 0; i < 4; i++)
            #pragma unroll
            for (int j = 0; j < 4; j++)
                acc[i][j] = __builtin_amdgcn_mfma_f32_16x16x32_bf16(af[i], bfr[j], acc[i][j], 0, 0, 0);
    }

    // C/D layout: col=lane&15, row=(lane>>4)*4+r  [m89/m91 verified]
    int rbase = seg * 4;
    #pragma unroll
    for (int i = 0; i < 4; i++) {
        #pragma unroll
        for (int r = 0; r < 4; r++) {
            int gm = m0 + wr * 64 + i * 16 + rbase + r;
            if (gm < M) {
                #pragma unroll
                for (int j = 0; j < 4; j++) {
                    int colL = wc * 64 + j * 16 + laneM;
                    if constexpr (DENSE) {
                        outf[(size_t)gm * CoutPad + n0 + colL] = acc[i][j][r];
                    } else {
                        cpart[((size_t)kzl * M + gm) * 128 + colL] = f2b(acc[i][j][r]);
                    }
                }
            }
        }
    }
}

static inline int div_up(int a, int b) { return (a + b - 1) / b; }

extern "C" void kernel_launch(void* const* d_in, const int* in_sizes, int n_in,
                              void* d_out, int out_size, void* d_ws, size_t ws_size,
                              hipStream_t stream) {
    const float* f0 = (const float*)d_in[0];
    const float* f1 = (const float*)d_in[1];
    const float* f2 = (const float*)d_in[2];
    const float* f3 = (const float*)d_in[3];
    const float* W_up2 = (const float*)d_in[4];
    const float* W_up1 = (const float*)d_in[5];
    const float* W_up0 = (const float*)d_in[6];
    const float* W_s0  = (const float*)d_in[7];
    const float* W_s1  = (const float*)d_in[8];
    const float* W_s2  = (const float*)d_in[9];
    const float* g_up2 = (const float*)d_in[10]; const float* b_up2 = (const float*)d_in[11];
    const float* g_up1 = (const float*)d_in[12]; const float* b_up1 = (const float*)d_in[13];
    const float* g_up0 = (const float*)d_in[14]; const float* b_up0 = (const float*)d_in[15];
    const float* g_s0  = (const float*)d_in[16]; const float* b_s0  = (const float*)d_in[17];
    const float* g_s1  = (const float*)d_in[18]; const float* b_s1  = (const float*)d_in[19];
    const float* g_s2  = (const float*)d_in[20]; const float* b_s2  = (const float*)d_in[21];
    const int* up2_in  = (const int*)d_in[22]; const int* up2_out = (const int*)d_in[23];
    const int* up1_in  = (const int*)d_in[24]; const int* up1_out = (const int*)d_in[25];
    const int* up0_in  = (const int*)d_in[26]; const int* up0_out = (const int*)d_in[27];
    const int* sm0_in  = (const int*)d_in[28]; const int* sm0_out = (const int*)d_in[29];
    const int* sm1_in  = (const int*)d_in[30]; const int* sm1_out = (const int*)d_in[31];

    char* ws = (char*)d_ws;
    auto alloc = [&](size_t bytes) { char* p = ws; ws += (bytes + 255) & ~(size_t)255; return p; };

    // weights bf16 WT[k][CoutPad][CinPad]
    unsigned short* WT_up2 = (unsigned short*)alloc((size_t)27 * 128 * 128 * 2);
    unsigned short* WT_up1 = (unsigned short*)alloc((size_t)27 * 256 * 192 * 2);
    unsigned short* WT_up0 = (unsigned short*)alloc((size_t)27 * 256 * 224 * 2);
    unsigned short* WT_s0  = (unsigned short*)alloc((size_t)27 * 512 * 256 * 2);
    unsigned short* WT_s1  = (unsigned short*)alloc((size_t)27 * 512 * 512 * 2);
    unsigned short* WT_s2  = (unsigned short*)alloc((size_t)512 * 512 * 2);
    // activations bf16
    unsigned short* xb3 = (unsigned short*)alloc((size_t)2000 * 128 * 2);
    unsigned short* xc2 = (unsigned short*)alloc((size_t)5000 * 192 * 2);
    unsigned short* xc1 = (unsigned short*)alloc((size_t)12000 * 224 * 2);
    unsigned short* xc0 = (unsigned short*)alloc((size_t)30000 * 256 * 2);
    unsigned short* ys  = (unsigned short*)alloc((size_t)30000 * 512 * 2);  // s0 out, then s1 out
    float* outb = (float*)alloc((size_t)30000 * 512 * 4);
    int* cnt = (int*)alloc((size_t)30000 * 4);
    int* ell = (int*)alloc((size_t)30000 * ELL_CAP * 4);
    float* stats = (float*)alloc((size_t)6 * 1024 * 4);
    // c partials (128-col chunk wide): everything that's left
    size_t used = (size_t)(ws - (char*)d_ws);
    size_t cBudget = (ws_size > used + (1u << 20)) ? (ws_size - used - (1u << 20)) : 0;
    unsigned short* c = (unsigned short*)ws;

    // ---- prep ----
    transpose_cast_w<<<dim3(4, 4, 27),  256, 0, stream>>>(W_up2, WT_up2, 128, 128, 128, 128);
    transpose_cast_w<<<dim3(8, 6, 27),  256, 0, stream>>>(W_up1, WT_up1, 192, 192, 192, 256);
    transpose_cast_w<<<dim3(8, 7, 27),  256, 0, stream>>>(W_up0, WT_up0, 224, 224, 224, 256);
    transpose_cast_w<<<dim3(16, 8, 27), 256, 0, stream>>>(W_s0,  WT_s0,  240, 512, 256, 512);
    transpose_cast_w<<<dim3(16, 16, 27),256, 0, stream>>>(W_s1,  WT_s1,  512, 512, 512, 512);
    transpose_cast_w<<<dim3(16, 16, 1), 256, 0, stream>>>(W_s2,  WT_s2,  512, 512, 512, 512);
    cast_cols<<<div_up(2000 * 128, 256), 256, 0, stream>>>(f3, xb3, 2000, 128, 128, 0, 128);
    hipMemsetAsync(stats, 0, (size_t)6 * 1024 * 4, stream);

    // sparse conv layer driver: 128-col N-chunks; K-chunk fallback if budget tight
    auto conv_layer = [&](const unsigned short* Ain, const unsigned short* WT,
                          const int* in_idx, const int* out_idx,
                          int M, int Kp, int CoutPad, int Cout, int Nout, float* statsL) {
        hipMemsetAsync(cnt, 0, (size_t)Nout * 4, stream);
        ell_build<<<div_up(27 * M, 256), 256, 0, stream>>>(out_idx, 27 * M, cnt, ell);
        size_t perK = (size_t)M * 128 * 2;
        int CK = (int)(cBudget / perK);
        if (CK < 1) CK = 1;
        if (CK > 27) CK = 27;
        for (int nb = 0; nb < CoutPad; nb += 128) {
            for (int k0 = 0; k0 < 27; k0 += CK) {
                int ck = (27 - k0 < CK) ? (27 - k0) : CK;
                spconv_gemm<false><<<dim3(div_up(M, 128), 1, ck), 256, 0, stream>>>(
                    Ain, WT, in_idx, c, nullptr, M, Kp, CoutPad, nb, k0);
                reduce_ell<<<div_up(Nout, 64), 256, 0, stream>>>(
                    c, cnt, ell, outb, statsL, nb, Cout, Nout,
                    k0 * M, (k0 + ck) * M, k0 > 0 ? 1 : 0, (k0 + ck) == 27 ? 1 : 0);
            }
        }
    };

    // ---- up2: xb3[2000,128] -> [5000,128]; concat f2 -> xc2[5000,192] ----
    conv_layer(xb3, WT_up2, up2_in, up2_out, 1600, 128, 128, 128, 5000, stats + 0 * 1024);
    bn_apply_bf16<<<div_up(5000 * 32, 256), 256, 0, stream>>>(outb, stats + 0 * 1024, g_up2, b_up2, xc2, 5000, 128, 192, 1.f / 5000);
    cast_cols<<<div_up(5000 * 64, 256), 256, 0, stream>>>(f2, xc2, 5000, 64, 192, 128, 64);

    // ---- up1: xc2[5000,192] -> [12000,192]; concat f1 -> xc1[12000,224] ----
    conv_layer(xc2, WT_up1, up1_in, up1_out, 4000, 192, 256, 192, 12000, stats + 1 * 1024);
    bn_apply_bf16<<<div_up(12000 * 48, 256), 256, 0, stream>>>(outb, stats + 1 * 1024, g_up1, b_up1, xc1, 12000, 192, 224, 1.f / 12000);
    cast_cols<<<div_up(12000 * 32, 256), 256, 0, stream>>>(f1, xc1, 12000, 32, 224, 192, 32);

    // ---- up0: xc1[12000,224] -> [30000,224]; concat f0+pad -> xc0[30000,256] ----
    conv_layer(xc1, WT_up0, up0_in, up0_out, 10000, 224, 256, 224, 30000, stats + 2 * 1024);
    bn_apply_bf16<<<div_up(30000 * 56, 256), 256, 0, stream>>>(outb, stats + 2 * 1024, g_up0, b_up0, xc0, 30000, 224, 256, 1.f / 30000);
    cast_cols<<<div_up(30000 * 32, 256), 256, 0, stream>>>(f0, xc0, 30000, 16, 256, 224, 32); // 16 real + 16 pad

    // ---- s0: xc0[30000,256] -> [30000,512] -> ys ----
    conv_layer(xc0, WT_s0, sm0_in, sm0_out, 10000, 256, 512, 512, 30000, stats + 3 * 1024);
    bn_apply_bf16<<<div_up(30000 * 128, 256), 256, 0, stream>>>(outb, stats + 3 * 1024, g_s0, b_s0, ys, 30000, 512, 512, 1.f / 30000);

    // ---- s1: ys[30000,512] -> [30000,512] -> ys (overwritten after reduce) ----
    conv_layer(ys, WT_s1, sm1_in, sm1_out, 10000, 512, 512, 512, 30000, stats + 4 * 1024);
    bn_apply_bf16<<<div_up(30000 * 128, 256), 256, 0, stream>>>(outb, stats + 4 * 1024, g_s1, b_s1, ys, 30000, 512, 512, 1.f / 30000);

    // ---- s2: dense ys[30000,512] @ W -> d_out, BN+ReLU in place ----
    float* out_f = (float*)d_out;
    spconv_gemm<true><<<dim3(235, 4, 1), 256, 0, stream>>>(ys, WT_s2, nullptr, nullptr, out_f, 30000, 512, 512, 0, 0);
    bn_stats<<<div_up(30000, 64), 256, 0, stream>>>(out_f, stats + 5 * 1024, 30000, 512, 64);
    bn_apply_f32<<<div_up(30000 * 128, 256), 256, 0, stream>>>(out_f, stats + 5 * 1024, g_s2, b_s2, 30000, 512, 1.f / 30000);
}

// Round 5
// 1495.266 us; speedup vs baseline: 3.6461x; 3.6461x over previous
//
#include <hip/hip_runtime.h>

typedef short bf16x8 __attribute__((ext_vector_type(8)));
typedef short bf16x4v __attribute__((ext_vector_type(4)));
typedef float f32x4 __attribute__((ext_vector_type(4)));

#define BN_EPS 1e-5f
#define ELL_CAP 64

__device__ __forceinline__ unsigned short f2b(float x) {
    union { float f; unsigned u; } v; v.f = x;
    unsigned r = v.u + 0x7FFFu + ((v.u >> 16) & 1u);
    return (unsigned short)(r >> 16);
}
__device__ __forceinline__ float b2f(unsigned short h) {
    union { unsigned u; float f; } v; v.u = ((unsigned)h) << 16;
    return v.f;
}
__device__ __forceinline__ void atomAddF(float* p, float v) { unsafeAtomicAdd(p, v); }

__device__ __forceinline__ void gload16(const void* g, void* l) {
    __builtin_amdgcn_global_load_lds((const __attribute__((address_space(1))) void*)g,
                                     (__attribute__((address_space(3))) void*)l, 16, 0, 0);
}

// ---- W[k][ci][co] f32 -> WT[k][coPad][ciPad] bf16 (zero-padded both dims) ----
__global__ void transpose_cast_w(const float* __restrict__ W, unsigned short* __restrict__ WT,
                                 int Cin, int Cout, int CinPad, int CoutPad) {
    __shared__ float t[32][33];
    int co0 = blockIdx.x * 32, ci0 = blockIdx.y * 32, k = blockIdx.z;
    const float* Wk = W + (size_t)k * Cin * Cout;
    unsigned short* WTk = WT + (size_t)k * CoutPad * CinPad;
    int tc = threadIdx.x & 31, tr = threadIdx.x >> 5;
    for (int i = 0; i < 4; i++) {
        int r = tr + i * 8;
        int ci = ci0 + r, co = co0 + tc;
        t[r][tc] = (ci < Cin && co < Cout) ? Wk[(size_t)ci * Cout + co] : 0.f;
    }
    __syncthreads();
    for (int i = 0; i < 4; i++) {
        int r = tr + i * 8;
        WTk[(size_t)(co0 + r) * CinPad + ci0 + tc] = f2b(t[tc][r]);
    }
}

// ---- cast fp32 [N,Csrc] -> bf16 dst[n*stride + off + j], zero-fill j>=Csrc ----
__global__ void cast_cols(const float* __restrict__ src, unsigned short* __restrict__ dst,
                          int N, int Csrc, int stride, int off, int wid) {
    int i = blockIdx.x * blockDim.x + threadIdx.x;
    if (i >= N * wid) return;
    int n = i / wid, j = i % wid;
    float v = (j < Csrc) ? src[(size_t)n * Csrc + j] : 0.f;
    dst[(size_t)n * stride + off + j] = f2b(v);
}

// ---- BN stats: per-channel sum & sumsq ----
__global__ void bn_stats(const float* __restrict__ x, float* __restrict__ stats,
                         int N, int C, int rowsPerBlock) {
    int r0 = blockIdx.x * rowsPerBlock;
    int r1 = min(N, r0 + rowsPerBlock);
    for (int c = threadIdx.x; c < C; c += blockDim.x) {
        float s = 0.f, s2 = 0.f;
        for (int r = r0; r < r1; r++) {
            float v = x[(size_t)r * C + c];
            s += v; s2 += v * v;
        }
        atomAddF(&stats[c], s);
        atomAddF(&stats[C + c], s2);
    }
}

// ---- BN apply + ReLU -> bf16 (strided dst, for concat), x4 vectorized ----
__global__ void bn_apply_bf16(const float* __restrict__ x, const float* __restrict__ stats,
                              const float* __restrict__ g, const float* __restrict__ b,
                              unsigned short* __restrict__ dst, int N, int C, int stride, float invN) {
    int i = blockIdx.x * blockDim.x + threadIdx.x;
    int C4 = C >> 2;
    if (i >= N * C4) return;
    int n = i / C4, cb = (i - n * C4) << 2;
    float4 xv = *(const float4*)(x + (size_t)n * C + cb);
    float vs[4] = {xv.x, xv.y, xv.z, xv.w};
    unsigned short os[4];
    #pragma unroll
    for (int j = 0; j < 4; j++) {
        int cc = cb + j;
        float mean = stats[cc] * invN;
        float var = stats[C + cc] * invN - mean * mean;
        float scale = g[cc] * rsqrtf(var + BN_EPS);
        float shift = b[cc] - mean * scale;
        os[j] = f2b(fmaxf(0.f, vs[j] * scale + shift));
    }
    ushort4 ov = {os[0], os[1], os[2], os[3]};
    *(ushort4*)(dst + (size_t)n * stride + cb) = ov;
}

// ---- BN apply + ReLU in-place fp32 (final output), x4 vectorized ----
__global__ void bn_apply_f32(float* __restrict__ x, const float* __restrict__ stats,
                             const float* __restrict__ g, const float* __restrict__ b,
                             int N, int C, float invN) {
    int i = blockIdx.x * blockDim.x + threadIdx.x;
    int C4 = C >> 2;
    if (i >= N * C4) return;
    int n = i / C4, cb = (i - n * C4) << 2;
    float* p = x + (size_t)n * C + cb;
    float4 xv = *(const float4*)p;
    float vs[4] = {xv.x, xv.y, xv.z, xv.w};
    #pragma unroll
    for (int j = 0; j < 4; j++) {
        int cc = cb + j;
        float mean = stats[cc] * invN;
        float var = stats[C + cc] * invN - mean * mean;
        float scale = g[cc] * rsqrtf(var + BN_EPS);
        float shift = b[cc] - mean * scale;
        vs[j] = fmaxf(0.f, vs[j] * scale + shift);
    }
    float4 ov = {vs[0], vs[1], vs[2], vs[3]};
    *(float4*)p = ov;
}

// ---- inverse-index (ELL) build: entry e = k*M+m ----
__global__ void ell_build(const int* __restrict__ out_idx, int total,
                          int* __restrict__ cnt, int* __restrict__ ell) {
    int e = blockIdx.x * blockDim.x + threadIdx.x;
    if (e >= total) return;
    int o = out_idx[e];
    int pos = atomicAdd(&cnt[o], 1);
    if (pos < ELL_CAP) ell[(size_t)o * ELL_CAP + pos] = e;
}

// ---- Phase B: one output row per QUARTER-WAVE (max rows in flight), 128-col chunk.
//      Split-column mapping: lane lm covers cols {lm*4, 64+lm*4} -> 8B loads in 128B
//      segments, float4 stores form full 256B lines. 2-deep pipelined entry loop. ----
__global__ __launch_bounds__(256)
void reduce_ell(const unsigned short* __restrict__ c, const int* __restrict__ cnt,
                const int* __restrict__ ell, float* __restrict__ out,
                int n0, int Cout, int Nout, int k0row, int k1row, int accum) {
    int tid = threadIdx.x;
    int o = blockIdx.x * 16 + (tid >> 4);
    if (o >= Nout) return;
    int lm = tid & 15;
    int c0 = lm * 4, c1 = 64 + lm * 4;
    int n = min(cnt[o], ELL_CAP);
    const int* er = ell + (size_t)o * ELL_CAP;
    float a0[4] = {0.f, 0.f, 0.f, 0.f}, a1[4] = {0.f, 0.f, 0.f, 0.f};
    int i = 0;
    for (; i + 1 < n; i += 2) {   // two independent partial-row loads in flight
        int e0 = er[i], e1 = er[i + 1];
        float m0 = (e0 >= k0row && e0 < k1row) ? 1.f : 0.f;
        float m1 = (e1 >= k0row && e1 < k1row) ? 1.f : 0.f;
        size_t r0 = (m0 != 0.f) ? (size_t)(e0 - k0row) : 0;
        size_t r1 = (m1 != 0.f) ? (size_t)(e1 - k0row) : 0;
        bf16x4v u00 = *(const bf16x4v*)(c + r0 * 128 + c0);
        bf16x4v u01 = *(const bf16x4v*)(c + r0 * 128 + c1);
        bf16x4v u10 = *(const bf16x4v*)(c + r1 * 128 + c0);
        bf16x4v u11 = *(const bf16x4v*)(c + r1 * 128 + c1);
        #pragma unroll
        for (int j = 0; j < 4; j++) {
            a0[j] += m0 * b2f((unsigned short)u00[j]) + m1 * b2f((unsigned short)u10[j]);
            a1[j] += m0 * b2f((unsigned short)u01[j]) + m1 * b2f((unsigned short)u11[j]);
        }
    }
    if (i < n) {
        int e0 = er[i];
        float m0 = (e0 >= k0row && e0 < k1row) ? 1.f : 0.f;
        size_t r0 = (m0 != 0.f) ? (size_t)(e0 - k0row) : 0;
        bf16x4v u00 = *(const bf16x4v*)(c + r0 * 128 + c0);
        bf16x4v u01 = *(const bf16x4v*)(c + r0 * 128 + c1);
        #pragma unroll
        for (int j = 0; j < 4; j++) {
            a0[j] += m0 * b2f((unsigned short)u00[j]);
            a1[j] += m0 * b2f((unsigned short)u01[j]);
        }
    }
    int g0 = n0 + c0, g1 = n0 + c1;
    if (g0 < Cout) {
        float* op = out + (size_t)o * Cout + g0;
        if (accum) { float4 x = *(const float4*)op; a0[0] += x.x; a0[1] += x.y; a0[2] += x.z; a0[3] += x.w; }
        float4 v = {a0[0], a0[1], a0[2], a0[3]};
        *(float4*)op = v;
    }
    if (g1 < Cout) {
        float* op = out + (size_t)o * Cout + g1;
        if (accum) { float4 x = *(const float4*)op; a1[0] += x.x; a1[1] += x.y; a1[2] += x.z; a1[3] += x.w; }
        float4 v = {a1[0], a1[1], a1[2], a1[3]};
        *(float4*)op = v;
    }
}

// ---- Phase A: per-k dense GEMM, 128x128 tile, BK=32, double-buffered LDS,
//      single barrier per K-iter (prefetch issued after barrier) ----
template<bool DENSE>
__global__ __launch_bounds__(256)
void spconv_gemm(const unsigned short* __restrict__ A, const unsigned short* __restrict__ BT,
                 const int* __restrict__ in_idx, unsigned short* __restrict__ cpart,
                 float* __restrict__ outf, int M, int Kp, int CoutPad, int nbase, int kbase) {
    // seg-major 16B chunks: chunk(seg,row) = seg*128+row; global_load_lds lane-ordered,
    // 2-way-max bank aliasing on ds_read_b128 (measured 0 conflicts in r3).
    __shared__ __align__(16) unsigned short As[2 * 4096];
    __shared__ __align__(16) unsigned short Bs[2 * 4096];
    int tid = threadIdx.x, wave = tid >> 6, lane = tid & 63;
    int wr = wave >> 1, wc = wave & 1;
    int m0 = blockIdx.x * 128;
    int n0 = nbase + blockIdx.y * 128;
    int kzl = blockIdx.z, kz = kbase + kzl;

    int r0 = m0 + lane, r1 = r0 + 64;
    size_t arow0, arow1;
    if constexpr (DENSE) {
        arow0 = (size_t)min(r0, M - 1);
        arow1 = (size_t)min(r1, M - 1);
    } else {
        const int* idxk = in_idx + (size_t)kz * M;
        arow0 = (r0 < M) ? (size_t)idxk[r0] : 0;
        arow1 = (r1 < M) ? (size_t)idxk[r1] : 0;
    }
    const unsigned short* gA0 = A + arow0 * Kp + wave * 8;
    const unsigned short* gA1 = A + arow1 * Kp + wave * 8;
    const unsigned short* BTk = BT + (size_t)kz * CoutPad * Kp;
    const unsigned short* gB0 = BTk + (size_t)(n0 + lane) * Kp + wave * 8;
    const unsigned short* gB1 = BTk + (size_t)(n0 + 64 + lane) * Kp + wave * 8;
    unsigned short* lA0 = As + (wave * 128) * 8;
    unsigned short* lA1 = As + (wave * 128 + 64) * 8;
    unsigned short* lB0 = Bs + (wave * 128) * 8;
    unsigned short* lB1 = Bs + (wave * 128 + 64) * 8;

    f32x4 acc[4][4];
    #pragma unroll
    for (int i = 0; i < 4; i++)
        #pragma unroll
        for (int j = 0; j < 4; j++) acc[i][j] = (f32x4)(0.f);

    int laneM = lane & 15, seg = lane >> 4;
    int aoff = (seg * 128 + wr * 64 + laneM) * 8;
    int boff = (seg * 128 + wc * 64 + laneM) * 8;

    // prologue: stage k-step 0 into buf 0
    gload16(gA0, lA0);
    gload16(gA1, lA1);
    gload16(gB0, lB0);
    gload16(gB1, lB1);

    int nIter = Kp >> 5;
    for (int t = 0; t < nIter; t++) {
        __syncthreads();   // buf[t&1] complete (vmcnt drained at barrier)
        if (t + 1 < nIter) {       // prefetch next k-step into the other buffer;
            int kc = (t + 1) * 32; // flies during this iteration's MFMA phase
            int bo = ((t + 1) & 1) * 4096;
            gload16(gA0 + kc, lA0 + bo);
            gload16(gA1 + kc, lA1 + bo);
            gload16(gB0 + kc, lB0 + bo);
            gload16(gB1 + kc, lB1 + bo);
        }
        const unsigned short* ab = As + (t & 1) * 4096 + aoff;
        const unsigned short* bb = Bs + (t & 1) * 4096 + boff;
        bf16x8 af[4], bfr[4];
        #pragma unroll
        for (int i = 0; i < 4; i++) af[i] = *(const bf16x8*)(ab + i * 128);
        #pragma unroll
        for (int j = 0; j < 4; j++) bfr[j] = *(const bf16x8*)(bb + j * 128);
        #pragma unroll
        for (int i = 0; i < 4; i++)
            #pragma unroll
            for (int j = 0; j < 4; j++)
                acc[i][j] = __builtin_amdgcn_mfma_f32_16x16x32_bf16(af[i], bfr[j], acc[i][j], 0, 0, 0);
    }

    // C/D layout: col=lane&15, row=(lane>>4)*4+r  [m89/m91 verified]
    int rbase = seg * 4;
    #pragma unroll
    for (int i = 0; i < 4; i++) {
        #pragma unroll
        for (int r = 0; r < 4; r++) {
            int gm = m0 + wr * 64 + i * 16 + rbase + r;
            if (gm < M) {
                #pragma unroll
                for (int j = 0; j < 4; j++) {
                    int colL = wc * 64 + j * 16 + laneM;
                    if constexpr (DENSE) {
                        outf[(size_t)gm * CoutPad + n0 + colL] = acc[i][j][r];
                    } else {
                        cpart[((size_t)kzl * M + gm) * 128 + colL] = f2b(acc[i][j][r]);
                    }
                }
            }
        }
    }
}

static inline int div_up(int a, int b) { return (a + b - 1) / b; }

extern "C" void kernel_launch(void* const* d_in, const int* in_sizes, int n_in,
                              void* d_out, int out_size, void* d_ws, size_t ws_size,
                              hipStream_t stream) {
    const float* f0 = (const float*)d_in[0];
    const float* f1 = (const float*)d_in[1];
    const float* f2 = (const float*)d_in[2];
    const float* f3 = (const float*)d_in[3];
    const float* W_up2 = (const float*)d_in[4];
    const float* W_up1 = (const float*)d_in[5];
    const float* W_up0 = (const float*)d_in[6];
    const float* W_s0  = (const float*)d_in[7];
    const float* W_s1  = (const float*)d_in[8];
    const float* W_s2  = (const float*)d_in[9];
    const float* g_up2 = (const float*)d_in[10]; const float* b_up2 = (const float*)d_in[11];
    const float* g_up1 = (const float*)d_in[12]; const float* b_up1 = (const float*)d_in[13];
    const float* g_up0 = (const float*)d_in[14]; const float* b_up0 = (const float*)d_in[15];
    const float* g_s0  = (const float*)d_in[16]; const float* b_s0  = (const float*)d_in[17];
    const float* g_s1  = (const float*)d_in[18]; const float* b_s1  = (const float*)d_in[19];
    const float* g_s2  = (const float*)d_in[20]; const float* b_s2  = (const float*)d_in[21];
    const int* up2_in  = (const int*)d_in[22]; const int* up2_out = (const int*)d_in[23];
    const int* up1_in  = (const int*)d_in[24]; const int* up1_out = (const int*)d_in[25];
    const int* up0_in  = (const int*)d_in[26]; const int* up0_out = (const int*)d_in[27];
    const int* sm0_in  = (const int*)d_in[28]; const int* sm0_out = (const int*)d_in[29];
    const int* sm1_in  = (const int*)d_in[30]; const int* sm1_out = (const int*)d_in[31];

    char* ws = (char*)d_ws;
    auto alloc = [&](size_t bytes) { char* p = ws; ws += (bytes + 255) & ~(size_t)255; return p; };

    // weights bf16 WT[k][CoutPad][CinPad]
    unsigned short* WT_up2 = (unsigned short*)alloc((size_t)27 * 128 * 128 * 2);
    unsigned short* WT_up1 = (unsigned short*)alloc((size_t)27 * 256 * 192 * 2);
    unsigned short* WT_up0 = (unsigned short*)alloc((size_t)27 * 256 * 224 * 2);
    unsigned short* WT_s0  = (unsigned short*)alloc((size_t)27 * 512 * 256 * 2);
    unsigned short* WT_s1  = (unsigned short*)alloc((size_t)27 * 512 * 512 * 2);
    unsigned short* WT_s2  = (unsigned short*)alloc((size_t)512 * 512 * 2);
    // activations bf16
    unsigned short* xb3 = (unsigned short*)alloc((size_t)2000 * 128 * 2);
    unsigned short* xc2 = (unsigned short*)alloc((size_t)5000 * 192 * 2);
    unsigned short* xc1 = (unsigned short*)alloc((size_t)12000 * 224 * 2);
    unsigned short* xc0 = (unsigned short*)alloc((size_t)30000 * 256 * 2);
    unsigned short* ys  = (unsigned short*)alloc((size_t)30000 * 512 * 2);  // s0 out, then s1 out
    float* outb = (float*)alloc((size_t)30000 * 512 * 4);
    int* cnt = (int*)alloc((size_t)30000 * 4);
    int* ell = (int*)alloc((size_t)30000 * ELL_CAP * 4);
    float* stats = (float*)alloc((size_t)6 * 1024 * 4);
    // c partials (128-col chunk wide): everything that's left
    size_t used = (size_t)(ws - (char*)d_ws);
    size_t cBudget = (ws_size > used + (1u << 20)) ? (ws_size - used - (1u << 20)) : 0;
    unsigned short* c = (unsigned short*)ws;

    // ---- prep ----
    transpose_cast_w<<<dim3(4, 4, 27),  256, 0, stream>>>(W_up2, WT_up2, 128, 128, 128, 128);
    transpose_cast_w<<<dim3(8, 6, 27),  256, 0, stream>>>(W_up1, WT_up1, 192, 192, 192, 256);
    transpose_cast_w<<<dim3(8, 7, 27),  256, 0, stream>>>(W_up0, WT_up0, 224, 224, 224, 256);
    transpose_cast_w<<<dim3(16, 8, 27), 256, 0, stream>>>(W_s0,  WT_s0,  240, 512, 256, 512);
    transpose_cast_w<<<dim3(16, 16, 27),256, 0, stream>>>(W_s1,  WT_s1,  512, 512, 512, 512);
    transpose_cast_w<<<dim3(16, 16, 1), 256, 0, stream>>>(W_s2,  WT_s2,  512, 512, 512, 512);
    cast_cols<<<div_up(2000 * 128, 256), 256, 0, stream>>>(f3, xb3, 2000, 128, 128, 0, 128);
    hipMemsetAsync(stats, 0, (size_t)6 * 1024 * 4, stream);

    // sparse conv layer driver: 128-col N-chunks, single k-pass (k-chunk fallback if tight)
    auto conv_layer = [&](const unsigned short* Ain, const unsigned short* WT,
                          const int* in_idx, const int* out_idx,
                          int M, int Kp, int CoutPad, int Cout, int Nout, float* statsL) {
        hipMemsetAsync(cnt, 0, (size_t)Nout * 4, stream);
        ell_build<<<div_up(27 * M, 256), 256, 0, stream>>>(out_idx, 27 * M, cnt, ell);
        size_t perK = (size_t)M * 128 * 2;
        int CK = (int)(cBudget / perK);
        if (CK < 1) CK = 1;
        if (CK > 27) CK = 27;
        for (int nb = 0; nb < CoutPad; nb += 128) {
            for (int k0 = 0; k0 < 27; k0 += CK) {
                int ck = (27 - k0 < CK) ? (27 - k0) : CK;
                spconv_gemm<false><<<dim3(div_up(M, 128), 1, ck), 256, 0, stream>>>(
                    Ain, WT, in_idx, c, nullptr, M, Kp, CoutPad, nb, k0);
                reduce_ell<<<div_up(Nout, 16), 256, 0, stream>>>(
                    c, cnt, ell, outb, nb, Cout, Nout, k0 * M, (k0 + ck) * M, k0 > 0 ? 1 : 0);
            }
        }
        bn_stats<<<div_up(Nout, 64), 256, 0, stream>>>(outb, statsL, Nout, Cout, 64);
    };

    // ---- up2: xb3[2000,128] -> [5000,128]; concat f2 -> xc2[5000,192] ----
    conv_layer(xb3, WT_up2, up2_in, up2_out, 1600, 128, 128, 128, 5000, stats + 0 * 1024);
    bn_apply_bf16<<<div_up(5000 * 32, 256), 256, 0, stream>>>(outb, stats + 0 * 1024, g_up2, b_up2, xc2, 5000, 128, 192, 1.f / 5000);
    cast_cols<<<div_up(5000 * 64, 256), 256, 0, stream>>>(f2, xc2, 5000, 64, 192, 128, 64);

    // ---- up1: xc2[5000,192] -> [12000,192]; concat f1 -> xc1[12000,224] ----
    conv_layer(xc2, WT_up1, up1_in, up1_out, 4000, 192, 256, 192, 12000, stats + 1 * 1024);
    bn_apply_bf16<<<div_up(12000 * 48, 256), 256, 0, stream>>>(outb, stats + 1 * 1024, g_up1, b_up1, xc1, 12000, 192, 224, 1.f / 12000);
    cast_cols<<<div_up(12000 * 32, 256), 256, 0, stream>>>(f1, xc1, 12000, 32, 224, 192, 32);

    // ---- up0: xc1[12000,224] -> [30000,224]; concat f0+pad -> xc0[30000,256] ----
    conv_layer(xc1, WT_up0, up0_in, up0_out, 10000, 224, 256, 224, 30000, stats + 2 * 1024);
    bn_apply_bf16<<<div_up(30000 * 56, 256), 256, 0, stream>>>(outb, stats + 2 * 1024, g_up0, b_up0, xc0, 30000, 224, 256, 1.f / 30000);
    cast_cols<<<div_up(30000 * 32, 256), 256, 0, stream>>>(f0, xc0, 30000, 16, 256, 224, 32); // 16 real + 16 pad

    // ---- s0: xc0[30000,256] -> [30000,512] -> ys ----
    conv_layer(xc0, WT_s0, sm0_in, sm0_out, 10000, 256, 512, 512, 30000, stats + 3 * 1024);
    bn_apply_bf16<<<div_up(30000 * 128, 256), 256, 0, stream>>>(outb, stats + 3 * 1024, g_s0, b_s0, ys, 30000, 512, 512, 1.f / 30000);

    // ---- s1: ys[30000,512] -> [30000,512] -> ys (overwritten after reduce) ----
    conv_layer(ys, WT_s1, sm1_in, sm1_out, 10000, 512, 512, 512, 30000, stats + 4 * 1024);
    bn_apply_bf16<<<div_up(30000 * 128, 256), 256, 0, stream>>>(outb, stats + 4 * 1024, g_s1, b_s1, ys, 30000, 512, 512, 1.f / 30000);

    // ---- s2: dense ys[30000,512] @ W -> d_out, BN+ReLU in place ----
    float* out_f = (float*)d_out;
    spconv_gemm<true><<<dim3(235, 4, 1), 256, 0, stream>>>(ys, WT_s2, nullptr, nullptr, out_f, 30000, 512, 512, 0, 0);
    bn_stats<<<div_up(30000, 64), 256, 0, stream>>>(out_f, stats + 5 * 1024, 30000, 512, 64);
    bn_apply_f32<<<div_up(30000 * 128, 256), 256, 0, stream>>>(out_f, stats + 5 * 1024, g_s2, b_s2, 30000, 512, 1.f / 30000);
}

// Round 6
// 1332.291 us; speedup vs baseline: 4.0922x; 1.1223x over previous
//
#include <hip/hip_runtime.h>

typedef short bf16x8 __attribute__((ext_vector_type(8)));
typedef float f32x4 __attribute__((ext_vector_type(4)));

#define BN_EPS 1e-5f
#define ELL_CAP 48

__device__ __forceinline__ unsigned short f2b(float x) {
    union { float f; unsigned u; } v; v.f = x;
    unsigned r = v.u + 0x7FFFu + ((v.u >> 16) & 1u);
    return (unsigned short)(r >> 16);
}
__device__ __forceinline__ float b2f(unsigned short h) {
    union { unsigned u; float f; } v; v.u = ((unsigned)h) << 16;
    return v.f;
}
__device__ __forceinline__ void atomAddF(float* p, float v) { unsafeAtomicAdd(p, v); }

__device__ __forceinline__ void gload16(const void* g, void* l) {
    __builtin_amdgcn_global_load_lds((const __attribute__((address_space(1))) void*)g,
                                     (__attribute__((address_space(3))) void*)l, 16, 0, 0);
}

// ---- W[k][ci][co] f32 -> WT[k][coPad][ciPad] bf16 (zero-padded both dims) ----
__global__ void transpose_cast_w(const float* __restrict__ W, unsigned short* __restrict__ WT,
                                 int Cin, int Cout, int CinPad, int CoutPad) {
    __shared__ float t[32][33];
    int co0 = blockIdx.x * 32, ci0 = blockIdx.y * 32, k = blockIdx.z;
    const float* Wk = W + (size_t)k * Cin * Cout;
    unsigned short* WTk = WT + (size_t)k * CoutPad * CinPad;
    int tc = threadIdx.x & 31, tr = threadIdx.x >> 5;
    for (int i = 0; i < 4; i++) {
        int r = tr + i * 8;
        int ci = ci0 + r, co = co0 + tc;
        t[r][tc] = (ci < Cin && co < Cout) ? Wk[(size_t)ci * Cout + co] : 0.f;
    }
    __syncthreads();
    for (int i = 0; i < 4; i++) {
        int r = tr + i * 8;
        WTk[(size_t)(co0 + r) * CinPad + ci0 + tc] = f2b(t[tc][r]);
    }
}

// ---- cast fp32 [N,Csrc] -> bf16 dst[n*stride + off + j], zero-fill j>=Csrc ----
__global__ void cast_cols(const float* __restrict__ src, unsigned short* __restrict__ dst,
                          int N, int Csrc, int stride, int off, int wid) {
    int i = blockIdx.x * blockDim.x + threadIdx.x;
    if (i >= N * wid) return;
    int n = i / wid, j = i % wid;
    float v = (j < Csrc) ? src[(size_t)n * Csrc + j] : 0.f;
    dst[(size_t)n * stride + off + j] = f2b(v);
}

// ---- BN stats over bf16 activations ----
__global__ void bn_stats_bf16(const unsigned short* __restrict__ x, float* __restrict__ stats,
                              int N, int C, int rowsPerBlock) {
    int r0 = blockIdx.x * rowsPerBlock;
    int r1 = min(N, r0 + rowsPerBlock);
    for (int c = threadIdx.x; c < C; c += blockDim.x) {
        float s = 0.f, s2 = 0.f;
        for (int r = r0; r < r1; r++) {
            float v = b2f(x[(size_t)r * C + c]);
            s += v; s2 += v * v;
        }
        atomAddF(&stats[c], s);
        atomAddF(&stats[C + c], s2);
    }
}

// ---- BN stats over fp32 (dense s2 output) ----
__global__ void bn_stats(const float* __restrict__ x, float* __restrict__ stats,
                         int N, int C, int rowsPerBlock) {
    int r0 = blockIdx.x * rowsPerBlock;
    int r1 = min(N, r0 + rowsPerBlock);
    for (int c = threadIdx.x; c < C; c += blockDim.x) {
        float s = 0.f, s2 = 0.f;
        for (int r = r0; r < r1; r++) {
            float v = x[(size_t)r * C + c];
            s += v; s2 += v * v;
        }
        atomAddF(&stats[c], s);
        atomAddF(&stats[C + c], s2);
    }
}

// ---- BN apply + ReLU: bf16 src [N,C] -> bf16 dst (strided, for concat), x8 ----
__global__ void bn_apply_bb(const unsigned short* __restrict__ x, const float* __restrict__ stats,
                            const float* __restrict__ g, const float* __restrict__ b,
                            unsigned short* __restrict__ dst, int N, int C, int stride, float invN) {
    int i = blockIdx.x * blockDim.x + threadIdx.x;
    int C8 = C >> 3;
    if (i >= N * C8) return;
    int n = i / C8, cb = (i - n * C8) << 3;
    bf16x8 xv = *(const bf16x8*)(x + (size_t)n * C + cb);
    bf16x8 ov;
    #pragma unroll
    for (int j = 0; j < 8; j++) {
        int cc = cb + j;
        float mean = stats[cc] * invN;
        float var = stats[C + cc] * invN - mean * mean;
        float scale = g[cc] * rsqrtf(var + BN_EPS);
        float shift = b[cc] - mean * scale;
        ov[j] = (short)f2b(fmaxf(0.f, b2f((unsigned short)xv[j]) * scale + shift));
    }
    *(bf16x8*)(dst + (size_t)n * stride + cb) = ov;
}

// ---- BN apply + ReLU in-place fp32 (final output), x4 ----
__global__ void bn_apply_f32(float* __restrict__ x, const float* __restrict__ stats,
                             const float* __restrict__ g, const float* __restrict__ b,
                             int N, int C, float invN) {
    int i = blockIdx.x * blockDim.x + threadIdx.x;
    int C4 = C >> 2;
    if (i >= N * C4) return;
    int n = i / C4, cb = (i - n * C4) << 2;
    float* p = x + (size_t)n * C + cb;
    float4 xv = *(const float4*)p;
    float vs[4] = {xv.x, xv.y, xv.z, xv.w};
    #pragma unroll
    for (int j = 0; j < 4; j++) {
        int cc = cb + j;
        float mean = stats[cc] * invN;
        float var = stats[C + cc] * invN - mean * mean;
        float scale = g[cc] * rsqrtf(var + BN_EPS);
        float shift = b[cc] - mean * scale;
        vs[j] = fmaxf(0.f, vs[j] * scale + shift);
    }
    float4 ov = {vs[0], vs[1], vs[2], vs[3]};
    *(float4*)p = ov;
}

// ---- inverse-index (ELL) build: entry e = k*M+m ----
__global__ void ell_build(const int* __restrict__ out_idx, int total,
                          int* __restrict__ cnt, int* __restrict__ ell) {
    int e = blockIdx.x * blockDim.x + threadIdx.x;
    if (e >= total) return;
    int o = out_idx[e];
    int pos = atomicAdd(&cnt[o], 1);
    if (pos < ELL_CAP) ell[(size_t)o * ELL_CAP + pos] = e;
}

// ---- Phase B: sum bf16 partial rows per output row (CW-col chunk), write bf16.
//      One row per (CW/8)-lane group; NT loads (partials are read-once). ----
template<int CW>
__global__ __launch_bounds__(256)
void reduce_ell(const unsigned short* __restrict__ c, const int* __restrict__ cnt,
                const int* __restrict__ ell, unsigned short* __restrict__ outb,
                int nb, int Cout, int Nout, int k0row, int k1row, int accum) {
    constexpr int LPR = CW / 8;        // lanes per row
    constexpr int RPB = 256 / LPR;     // rows per block
    int tid = threadIdx.x;
    int o = blockIdx.x * RPB + tid / LPR;
    if (o >= Nout) return;
    int colL = (tid % LPR) * 8;
    int n = min(cnt[o], ELL_CAP);
    const int* er = ell + (size_t)o * ELL_CAP;
    float a[8] = {0.f, 0.f, 0.f, 0.f, 0.f, 0.f, 0.f, 0.f};
    int i = 0;
    for (; i + 1 < n; i += 2) {   // 2 independent partial-row loads in flight
        int e0 = er[i], e1 = er[i + 1];
        float m0 = (e0 >= k0row && e0 < k1row) ? 1.f : 0.f;
        float m1 = (e1 >= k0row && e1 < k1row) ? 1.f : 0.f;
        size_t r0 = (m0 != 0.f) ? (size_t)(e0 - k0row) : 0;
        size_t r1 = (m1 != 0.f) ? (size_t)(e1 - k0row) : 0;
        bf16x8 u0 = __builtin_nontemporal_load((const bf16x8*)(c + r0 * CW + colL));
        bf16x8 u1 = __builtin_nontemporal_load((const bf16x8*)(c + r1 * CW + colL));
        #pragma unroll
        for (int j = 0; j < 8; j++)
            a[j] += m0 * b2f((unsigned short)u0[j]) + m1 * b2f((unsigned short)u1[j]);
    }
    if (i < n) {
        int e0 = er[i];
        float m0 = (e0 >= k0row && e0 < k1row) ? 1.f : 0.f;
        size_t r0 = (m0 != 0.f) ? (size_t)(e0 - k0row) : 0;
        bf16x8 u0 = __builtin_nontemporal_load((const bf16x8*)(c + r0 * CW + colL));
        #pragma unroll
        for (int j = 0; j < 8; j++) a[j] += m0 * b2f((unsigned short)u0[j]);
    }
    int gc = nb + colL;
    if (gc < Cout) {   // Cout % 8 == 0 so whole 8-group is in-range
        unsigned short* op = outb + (size_t)o * Cout + gc;
        if (accum) {
            bf16x8 prev = *(const bf16x8*)op;
            #pragma unroll
            for (int j = 0; j < 8; j++) a[j] += b2f((unsigned short)prev[j]);
        }
        bf16x8 w;
        #pragma unroll
        for (int j = 0; j < 8; j++) w[j] = (short)f2b(a[j]);
        *(bf16x8*)op = w;
    }
}

// ---- Phase A: per-k gather GEMM, 128xTN tile, BK=32, double-buffered LDS,
//      global_load_lds staging, NT partial stores ----
template<int TN, bool DENSE>
__global__ __launch_bounds__(256, 2)
void spconv_gemm(const unsigned short* __restrict__ A, const unsigned short* __restrict__ BT,
                 const int* __restrict__ in_idx, unsigned short* __restrict__ cpart,
                 float* __restrict__ outf, int M, int Kp, int CoutPad, int nbase, int kbase) {
    constexpr int WN = TN / 32;        // B frags per wave
    constexpr int NB = TN / 64;        // B staging groups per thread
    constexpr int BUFA = 128 * 32;     // shorts per A buffer
    constexpr int BUFB = TN * 32;      // shorts per B buffer
    // seg-major 16B chunks: chunk(seg,row) = seg*128+row (A), seg*TN+col (B):
    // global_load_lds lane-ordered AND 2-way-max bank aliasing on ds_read_b128.
    __shared__ __align__(16) unsigned short As[2 * BUFA];
    __shared__ __align__(16) unsigned short Bs[2 * BUFB];
    int tid = threadIdx.x, wave = tid >> 6, lane = tid & 63;
    int wr = wave >> 1, wc = wave & 1;
    int m0 = blockIdx.x * 128;
    int n0 = nbase + blockIdx.y * TN;
    int kzl = blockIdx.z, kz = kbase + kzl;

    int r0 = m0 + lane, r1 = r0 + 64;
    size_t arow0, arow1;
    if constexpr (DENSE) {
        arow0 = (size_t)min(r0, M - 1);
        arow1 = (size_t)min(r1, M - 1);
    } else {
        const int* idxk = in_idx + (size_t)kz * M;
        arow0 = (r0 < M) ? (size_t)idxk[r0] : 0;
        arow1 = (r1 < M) ? (size_t)idxk[r1] : 0;
    }
    const unsigned short* gA0 = A + arow0 * Kp + wave * 8;
    const unsigned short* gA1 = A + arow1 * Kp + wave * 8;
    const unsigned short* BTk = BT + (size_t)kz * CoutPad * Kp;
    const unsigned short* gB[NB];
    unsigned short* lB[NB];
    #pragma unroll
    for (int t = 0; t < NB; t++) {
        gB[t] = BTk + (size_t)(n0 + t * 64 + lane) * Kp + wave * 8;
        lB[t] = Bs + (size_t)(wave * TN + t * 64) * 8;
    }
    unsigned short* lA0 = As + (wave * 128) * 8;
    unsigned short* lA1 = As + (wave * 128 + 64) * 8;

    f32x4 acc[4][WN];
    #pragma unroll
    for (int i = 0; i < 4; i++)
        #pragma unroll
        for (int j = 0; j < WN; j++) acc[i][j] = (f32x4)(0.f);

    int laneM = lane & 15, seg = lane >> 4;
    int aoff = (seg * 128 + wr * 64 + laneM) * 8;
    int boff = (seg * TN + wc * (TN / 2) + laneM) * 8;

    // prologue: stage k-step 0 into buf 0
    gload16(gA0, lA0);
    gload16(gA1, lA1);
    #pragma unroll
    for (int t = 0; t < NB; t++) gload16(gB[t], lB[t]);

    int nIter = Kp >> 5;
    for (int t = 0; t < nIter; t++) {
        __syncthreads();   // buf[t&1] complete (vmcnt drained at barrier)
        if (t + 1 < nIter) {       // prefetch next k-step into the other buffer
            int kc = (t + 1) * 32;
            int boA = ((t + 1) & 1) * BUFA;
            int boB = ((t + 1) & 1) * BUFB;
            gload16(gA0 + kc, lA0 + boA);
            gload16(gA1 + kc, lA1 + boA);
            #pragma unroll
            for (int q = 0; q < NB; q++) gload16(gB[q] + kc, lB[q] + boB);
        }
        const unsigned short* ab = As + (t & 1) * BUFA + aoff;
        const unsigned short* bb = Bs + (t & 1) * BUFB + boff;
        bf16x8 af[4], bfr[WN];
        #pragma unroll
        for (int i = 0; i < 4; i++) af[i] = *(const bf16x8*)(ab + i * 128);
        #pragma unroll
        for (int j = 0; j < WN; j++) bfr[j] = *(const bf16x8*)(bb + j * 128);
        #pragma unroll
        for (int i = 0; i < 4; i++)
            #pragma unroll
            for (int j = 0; j < WN; j++)
                acc[i][j] = __builtin_amdgcn_mfma_f32_16x16x32_bf16(af[i], bfr[j], acc[i][j], 0, 0, 0);
    }

    // C/D layout: col=lane&15, row=(lane>>4)*4+r  [m89/m91 verified]
    int rbase = seg * 4;
    #pragma unroll
    for (int i = 0; i < 4; i++) {
        #pragma unroll
        for (int r = 0; r < 4; r++) {
            int gm = m0 + wr * 64 + i * 16 + rbase + r;
            if (gm < M) {
                #pragma unroll
                for (int j = 0; j < WN; j++) {
                    int colL = wc * (TN / 2) + j * 16 + laneM;
                    if constexpr (DENSE) {
                        outf[(size_t)gm * CoutPad + n0 + colL] = acc[i][j][r];
                    } else {
                        __builtin_nontemporal_store(
                            (unsigned short)f2b(acc[i][j][r]),
                            &cpart[((size_t)kzl * M + gm) * TN + colL]);
                    }
                }
            }
        }
    }
}

static inline int div_up(int a, int b) { return (a + b - 1) / b; }

extern "C" void kernel_launch(void* const* d_in, const int* in_sizes, int n_in,
                              void* d_out, int out_size, void* d_ws, size_t ws_size,
                              hipStream_t stream) {
    const float* f0 = (const float*)d_in[0];
    const float* f1 = (const float*)d_in[1];
    const float* f2 = (const float*)d_in[2];
    const float* f3 = (const float*)d_in[3];
    const float* W_up2 = (const float*)d_in[4];
    const float* W_up1 = (const float*)d_in[5];
    const float* W_up0 = (const float*)d_in[6];
    const float* W_s0  = (const float*)d_in[7];
    const float* W_s1  = (const float*)d_in[8];
    const float* W_s2  = (const float*)d_in[9];
    const float* g_up2 = (const float*)d_in[10]; const float* b_up2 = (const float*)d_in[11];
    const float* g_up1 = (const float*)d_in[12]; const float* b_up1 = (const float*)d_in[13];
    const float* g_up0 = (const float*)d_in[14]; const float* b_up0 = (const float*)d_in[15];
    const float* g_s0  = (const float*)d_in[16]; const float* b_s0  = (const float*)d_in[17];
    const float* g_s1  = (const float*)d_in[18]; const float* b_s1  = (const float*)d_in[19];
    const float* g_s2  = (const float*)d_in[20]; const float* b_s2  = (const float*)d_in[21];
    const int* up2_in  = (const int*)d_in[22]; const int* up2_out = (const int*)d_in[23];
    const int* up1_in  = (const int*)d_in[24]; const int* up1_out = (const int*)d_in[25];
    const int* up0_in  = (const int*)d_in[26]; const int* up0_out = (const int*)d_in[27];
    const int* sm0_in  = (const int*)d_in[28]; const int* sm0_out = (const int*)d_in[29];
    const int* sm1_in  = (const int*)d_in[30]; const int* sm1_out = (const int*)d_in[31];

    char* ws = (char*)d_ws;
    auto alloc = [&](size_t bytes) { char* p = ws; ws += (bytes + 255) & ~(size_t)255; return p; };

    // shared weight buffer (transposed per layer right before use; stream-serialized)
    unsigned short* WT = (unsigned short*)alloc((size_t)27 * 512 * 512 * 2);  // 14.2 MB max (s1)
    // activations bf16
    unsigned short* xb3 = (unsigned short*)alloc((size_t)2000 * 128 * 2);
    unsigned short* xc2 = (unsigned short*)alloc((size_t)5000 * 192 * 2);
    unsigned short* xc1 = (unsigned short*)alloc((size_t)12000 * 224 * 2);
    unsigned short* xc0 = (unsigned short*)alloc((size_t)30000 * 256 * 2);
    unsigned short* ys  = (unsigned short*)alloc((size_t)30000 * 512 * 2);  // s0 out, then s1 out
    unsigned short* outb = (unsigned short*)alloc((size_t)30000 * 512 * 2); // bf16 conv result
    int* cnt = (int*)alloc((size_t)30000 * 4);
    int* ell = (int*)alloc((size_t)30000 * ELL_CAP * 4);
    float* stats = (float*)alloc((size_t)6 * 1024 * 4);
    // c partials: everything that's left
    size_t used = (size_t)(ws - (char*)d_ws);
    size_t cBudget = (ws_size > used + (1u << 20)) ? (ws_size - used - (1u << 20)) : 0;
    unsigned short* c = (unsigned short*)ws;

    hipMemsetAsync(stats, 0, (size_t)6 * 1024 * 4, stream);
    cast_cols<<<div_up(2000 * 128, 256), 256, 0, stream>>>(f3, xb3, 2000, 128, 128, 0, 128);

    // TN=256 sparse layer driver (single n-chunk covers CoutPad<=256; else 2 chunks)
    auto conv256 = [&](const unsigned short* Ain, const int* in_idx, const int* out_idx,
                       int M, int Kp, int CoutPad, int Cout, int Nout, float* statsL) {
        hipMemsetAsync(cnt, 0, (size_t)Nout * 4, stream);
        ell_build<<<div_up(27 * M, 256), 256, 0, stream>>>(out_idx, 27 * M, cnt, ell);
        size_t perK = (size_t)M * 256 * 2;
        int CK = (int)(cBudget / perK);
        if (CK < 1) CK = 1;
        if (CK > 27) CK = 27;
        for (int nb = 0; nb < CoutPad; nb += 256) {
            for (int k0 = 0; k0 < 27; k0 += CK) {
                int ck = (27 - k0 < CK) ? (27 - k0) : CK;
                spconv_gemm<256, false><<<dim3(div_up(M, 128), 1, ck), 256, 0, stream>>>(
                    Ain, WT, in_idx, c, nullptr, M, Kp, CoutPad, nb, k0);
                reduce_ell<256><<<div_up(Nout, 8), 256, 0, stream>>>(
                    c, cnt, ell, outb, nb, Cout, Nout, k0 * M, (k0 + ck) * M, k0 > 0 ? 1 : 0);
            }
        }
        bn_stats_bf16<<<div_up(Nout, 64), 256, 0, stream>>>(outb, statsL, Nout, Cout, 64);
    };

    // ---- up2 (TN=128): xb3[2000,128] -> [5000,128]; concat f2 -> xc2[5000,192] ----
    transpose_cast_w<<<dim3(4, 4, 27), 256, 0, stream>>>(W_up2, WT, 128, 128, 128, 128);
    hipMemsetAsync(cnt, 0, (size_t)5000 * 4, stream);
    ell_build<<<div_up(27 * 1600, 256), 256, 0, stream>>>(up2_out, 27 * 1600, cnt, ell);
    spconv_gemm<128, false><<<dim3(13, 1, 27), 256, 0, stream>>>(xb3, WT, up2_in, c, nullptr, 1600, 128, 128, 0, 0);
    reduce_ell<128><<<div_up(5000, 16), 256, 0, stream>>>(c, cnt, ell, outb, 0, 128, 5000, 0, 27 * 1600, 0);
    bn_stats_bf16<<<div_up(5000, 64), 256, 0, stream>>>(outb, stats + 0 * 1024, 5000, 128, 64);
    bn_apply_bb<<<div_up(5000 * 16, 256), 256, 0, stream>>>(outb, stats + 0 * 1024, g_up2, b_up2, xc2, 5000, 128, 192, 1.f / 5000);
    cast_cols<<<div_up(5000 * 64, 256), 256, 0, stream>>>(f2, xc2, 5000, 64, 192, 128, 64);

    // ---- up1: xc2[5000,192] -> [12000,192]; concat f1 -> xc1[12000,224] ----
    transpose_cast_w<<<dim3(8, 6, 27), 256, 0, stream>>>(W_up1, WT, 192, 192, 192, 256);
    conv256(xc2, up1_in, up1_out, 4000, 192, 256, 192, 12000, stats + 1 * 1024);
    bn_apply_bb<<<div_up(12000 * 24, 256), 256, 0, stream>>>(outb, stats + 1 * 1024, g_up1, b_up1, xc1, 12000, 192, 224, 1.f / 12000);
    cast_cols<<<div_up(12000 * 32, 256), 256, 0, stream>>>(f1, xc1, 12000, 32, 224, 192, 32);

    // ---- up0: xc1[12000,224] -> [30000,224]; concat f0+pad -> xc0[30000,256] ----
    transpose_cast_w<<<dim3(8, 7, 27), 256, 0, stream>>>(W_up0, WT, 224, 224, 224, 256);
    conv256(xc1, up0_in, up0_out, 10000, 224, 256, 224, 30000, stats + 2 * 1024);
    bn_apply_bb<<<div_up(30000 * 28, 256), 256, 0, stream>>>(outb, stats + 2 * 1024, g_up0, b_up0, xc0, 30000, 224, 256, 1.f / 30000);
    cast_cols<<<div_up(30000 * 32, 256), 256, 0, stream>>>(f0, xc0, 30000, 16, 256, 224, 32); // 16 real + 16 pad

    // ---- s0: xc0[30000,256] -> [30000,512] -> ys ----
    transpose_cast_w<<<dim3(16, 8, 27), 256, 0, stream>>>(W_s0, WT, 240, 512, 256, 512);
    conv256(xc0, sm0_in, sm0_out, 10000, 256, 512, 512, 30000, stats + 3 * 1024);
    bn_apply_bb<<<div_up(30000 * 64, 256), 256, 0, stream>>>(outb, stats + 3 * 1024, g_s0, b_s0, ys, 30000, 512, 512, 1.f / 30000);

    // ---- s1: ys[30000,512] -> [30000,512] -> ys ----
    transpose_cast_w<<<dim3(16, 16, 27), 256, 0, stream>>>(W_s1, WT, 512, 512, 512, 512);
    conv256(ys, sm1_in, sm1_out, 10000, 512, 512, 512, 30000, stats + 4 * 1024);
    bn_apply_bb<<<div_up(30000 * 64, 256), 256, 0, stream>>>(outb, stats + 4 * 1024, g_s1, b_s1, ys, 30000, 512, 512, 1.f / 30000);

    // ---- s2: dense ys[30000,512] @ W -> d_out, BN+ReLU in place ----
    transpose_cast_w<<<dim3(16, 16, 1), 256, 0, stream>>>(W_s2, WT, 512, 512, 512, 512);
    float* out_f = (float*)d_out;
    spconv_gemm<256, true><<<dim3(235, 2, 1), 256, 0, stream>>>(ys, WT, nullptr, nullptr, out_f, 30000, 512, 512, 0, 0);
    bn_stats<<<div_up(30000, 64), 256, 0, stream>>>(out_f, stats + 5 * 1024, 30000, 512, 64);
    bn_apply_f32<<<div_up(30000 * 128, 256), 256, 0, stream>>>(out_f, stats + 5 * 1024, g_s2, b_s2, 30000, 512, 1.f / 30000);
}